// Round 1
// baseline (259.294 us; speedup 1.0000x reference)
//
#include <hip/hip_runtime.h>

// ---------------------------------------------------------------------------
// Fused NeRF MLP forward: 262144 rows, 63-in, 8x256 hidden + skip at L4->L5,
// 4-dim output. fp16 MFMA (16x16x32) with fp32 accumulation.
//
// Layout strategy:
//  - Weights prepped per-launch (nerf_prep) into fragment-linear fp16 in d_ws:
//    wf[((ks*NF + nf)*64 + lane)*8 + i] = W[k][n],
//    k = ks*32 + (lane>>4)*8 + i, n = nf*16 + (lane&15).
//    Same k-bijection used for A and B fragments -> result independent of the
//    hardware's internal K slot mapping (only C layout must be exact).
//  - Layer-5 skip concat folded into weight prep k-permutation:
//    k' in [0,256) = h part (orig rows 63..318), k' in [256,319) = x part.
//  - Activations live in LDS (hbuf[64][264] fp16, padded to dodge bank
//    conflicts); x (63 cols, padded to 64) staged once in xbuf.
//  - 4 waves/WG split the 256 output cols; final 256->4 layer is row-split.
// ---------------------------------------------------------------------------

typedef _Float16 h8 __attribute__((ext_vector_type(8)));
typedef float f4 __attribute__((ext_vector_type(4)));

// fragment-linear weight offsets, in halves (half-groups = offset/8):
// L0 K=64, L1..L4 K=256, L5 K=320, L6,L7 K=256, OUT K=256 (NF=1, n padded to 16)
#define OFF_L0   0
#define OFF_L1   16384
#define OFF_L2   81920
#define OFF_L3   147456
#define OFF_L4   212992
#define OFF_L5   278528
#define OFF_L6   360448
#define OFF_L7   425984
#define OFF_OUT  491520
#define TOT_HALVES 495616
#define TOT_GROUPS (TOT_HALVES / 8)   // 61952

__global__ void nerf_prep(const float* __restrict__ W0, const float* __restrict__ W1,
                          const float* __restrict__ W2, const float* __restrict__ W3,
                          const float* __restrict__ W4, const float* __restrict__ W5,
                          const float* __restrict__ W6, const float* __restrict__ W7,
                          const float* __restrict__ Wout, _Float16* __restrict__ wf)
{
    int g = blockIdx.x * 256 + threadIdx.x;     // one 8-half fragment group
    if (g >= TOT_GROUPS) return;

    const int bounds[10] = {0, 2048, 10240, 18432, 26624, 34816, 45056, 53248, 61440, 61952};
    const float* Ws[9] = {W0, W1, W2, W3, W4, W5, W6, W7, Wout};

    int L = 0;
    while (L < 8 && g >= bounds[L + 1]) ++L;

    int t    = g - bounds[L];
    int lane = t & 63;
    int q    = t >> 6;
    int NF   = (L == 8) ? 1 : 16;
    int nf   = q % NF;
    int ks   = q / NF;
    int n    = nf * 16 + (lane & 15);
    int k0   = ks * 32 + (lane >> 4) * 8;

    const float* W = Ws[L];
    h8 v;
#pragma unroll
    for (int i = 0; i < 8; ++i) {
        int k = k0 + i;
        float val = 0.f;
        if (L == 0) {
            if (k < 63) val = W[k * 256 + n];                 // 63x256, pad k=63
        } else if (L == 5) {
            // k' < 256 -> h part (orig row 63+k'); k' >= 256 -> x part (orig row k'-256)
            if (k < 256)            val = W[(63 + k) * 256 + n];
            else if ((k - 256) < 63) val = W[(k - 256) * 256 + n];
        } else if (L == 8) {
            if (n < 4) val = W[k * 4 + n];                    // 256x4, pad n to 16
        } else {
            val = W[k * 256 + n];                             // 256x256
        }
        v[i] = (_Float16)val;
    }
    *(h8*)(wf + (size_t)g * 8) = v;
}

// MODE: 0 = A from hbuf, 1 = A from xbuf (layer 0), 2 = hbuf then xbuf (layer 5)
template <int KSTEPS, int MODE>
__device__ __forceinline__ void mlp_layer(_Float16 (&hbuf)[64][264], _Float16 (&xbuf)[64][72],
                                          const _Float16* __restrict__ wfrag,
                                          const float* __restrict__ bias,
                                          int wid, int lane)
{
    const int lg = lane >> 4, ln = lane & 15;

    f4 acc[4][4];
#pragma unroll
    for (int mf = 0; mf < 4; ++mf)
#pragma unroll
        for (int nf = 0; nf < 4; ++nf)
#pragma unroll
            for (int i = 0; i < 4; ++i) acc[mf][nf][i] = 0.f;

#pragma unroll
    for (int ks = 0; ks < KSTEPS; ++ks) {
        h8 bfr[4];
#pragma unroll
        for (int nf = 0; nf < 4; ++nf)
            bfr[nf] = *(const h8*)(wfrag + (size_t)((ks * 16 + (wid * 4 + nf)) * 64 + lane) * 8);

#pragma unroll
        for (int mf = 0; mf < 4; ++mf) {
            const _Float16* ap;
            if constexpr (MODE == 1) {
                ap = &xbuf[mf * 16 + ln][ks * 32 + lg * 8];
            } else if constexpr (MODE == 2) {
                ap = (ks < 8) ? &hbuf[mf * 16 + ln][ks * 32 + lg * 8]
                              : &xbuf[mf * 16 + ln][(ks - 8) * 32 + lg * 8];
            } else {
                ap = &hbuf[mf * 16 + ln][ks * 32 + lg * 8];
            }
            h8 afr = *(const h8*)ap;
#pragma unroll
            for (int nf = 0; nf < 4; ++nf)
                acc[mf][nf] = __builtin_amdgcn_mfma_f32_16x16x32_f16(afr, bfr[nf], acc[mf][nf], 0, 0, 0);
        }
    }

    __syncthreads();   // everyone done reading hbuf -> safe to overwrite in place

#pragma unroll
    for (int nf = 0; nf < 4; ++nf) {
        float bv = bias[wid * 64 + nf * 16 + ln];
#pragma unroll
        for (int mf = 0; mf < 4; ++mf) {
#pragma unroll
            for (int i = 0; i < 4; ++i) {
                float v = acc[mf][nf][i] + bv;      // bias in fp32
                v = fmaxf(v, 0.f);                  // relu in fp32
                // C layout (m89-verified): row = (lane>>4)*4 + reg, col = lane&15
                hbuf[mf * 16 + lg * 4 + i][wid * 64 + nf * 16 + ln] = (_Float16)v;
            }
        }
    }
    __syncthreads();
}

__global__ __launch_bounds__(256, 2) void nerf_fused(
    const float* __restrict__ x,
    const float* __restrict__ b0, const float* __restrict__ b1, const float* __restrict__ b2,
    const float* __restrict__ b3, const float* __restrict__ b4, const float* __restrict__ b5,
    const float* __restrict__ b6, const float* __restrict__ b7, const float* __restrict__ bout,
    const _Float16* __restrict__ wf,
    float* __restrict__ out)
{
    __shared__ _Float16 hbuf[64][264];   // 256 + 8 pad halves per row
    __shared__ _Float16 xbuf[64][72];    // 64 (63 real + 1 zero) + pad

    const int tid  = threadIdx.x;
    const int wid  = tid >> 6;
    const int lane = tid & 63;
    const int lg   = lane >> 4, ln = lane & 15;
    const int row0 = blockIdx.x * 64;

    // stage x[:, 0:63] -> fp16, zero-pad col 63
    for (int idx = tid; idx < 64 * 64; idx += 256) {
        int r = idx >> 6, c = idx & 63;
        float v = (c < 63) ? x[(size_t)(row0 + r) * 90 + c] : 0.f;
        xbuf[r][c] = (_Float16)v;
    }
    __syncthreads();

    mlp_layer<2, 1>(hbuf, xbuf, wf + OFF_L0, b0, wid, lane);
    mlp_layer<8, 0>(hbuf, xbuf, wf + OFF_L1, b1, wid, lane);
    mlp_layer<8, 0>(hbuf, xbuf, wf + OFF_L2, b2, wid, lane);
    mlp_layer<8, 0>(hbuf, xbuf, wf + OFF_L3, b3, wid, lane);
    mlp_layer<8, 0>(hbuf, xbuf, wf + OFF_L4, b4, wid, lane);
    mlp_layer<10, 2>(hbuf, xbuf, wf + OFF_L5, b5, wid, lane);
    mlp_layer<8, 0>(hbuf, xbuf, wf + OFF_L6, b6, wid, lane);
    mlp_layer<8, 0>(hbuf, xbuf, wf + OFF_L7, b7, wid, lane);

    // output layer 256 -> 4 (padded to 16 cols), row-split: wave wid owns rows [16*wid, 16*wid+16)
    f4 oacc;
#pragma unroll
    for (int i = 0; i < 4; ++i) oacc[i] = 0.f;
#pragma unroll
    for (int ks = 0; ks < 8; ++ks) {
        h8 bfr = *(const h8*)(wf + OFF_OUT + (size_t)(ks * 64 + lane) * 8);
        h8 afr = *(const h8*)&hbuf[wid * 16 + ln][ks * 32 + lg * 8];
        oacc = __builtin_amdgcn_mfma_f32_16x16x32_f16(afr, bfr, oacc, 0, 0, 0);
    }
    if (ln < 4) {
        float bo = bout[ln];
#pragma unroll
        for (int i = 0; i < 4; ++i) {
            int r = row0 + wid * 16 + lg * 4 + i;
            out[(size_t)r * 4 + ln] = oacc[i] + bo;
        }
    }
}

extern "C" void kernel_launch(void* const* d_in, const int* in_sizes, int n_in,
                              void* d_out, int out_size, void* d_ws, size_t ws_size,
                              hipStream_t stream)
{
    const float* x = (const float*)d_in[0];
    const float* W[9];
    const float* b[9];
    for (int i = 0; i < 8; ++i) {
        W[i] = (const float*)d_in[1 + 2 * i];
        b[i] = (const float*)d_in[2 + 2 * i];
    }
    W[8] = (const float*)d_in[17];   // Wout
    b[8] = (const float*)d_in[18];   // bout

    _Float16* wf = (_Float16*)d_ws;

    nerf_prep<<<(TOT_GROUPS + 255) / 256, 256, 0, stream>>>(
        W[0], W[1], W[2], W[3], W[4], W[5], W[6], W[7], W[8], wf);

    nerf_fused<<<262144 / 64, 256, 0, stream>>>(
        x, b[0], b[1], b[2], b[3], b[4], b[5], b[6], b[7], b[8], wf,
        (float*)d_out);
}

// Round 2
// 237.970 us; speedup vs baseline: 1.0896x; 1.0896x over previous
//
#include <hip/hip_runtime.h>

// ---------------------------------------------------------------------------
// Fused NeRF MLP forward: 262144 rows, 63-in, 8x256 hidden + skip at L4->L5,
// 4-dim output. fp16 MFMA (16x16x32) with fp32 accumulation.
//
// R2: depth-2 software pipeline on B-fragment (weight) global loads, carried
// across the layer barrier (register-dest loads survive s_barrier). Bias
// loads hoisted to layer start. Everything else identical to R1.
// ---------------------------------------------------------------------------

typedef _Float16 h8 __attribute__((ext_vector_type(8)));
typedef float f4 __attribute__((ext_vector_type(4)));

// fragment-linear weight offsets, in halves (half-groups = offset/8):
// L0 K=64, L1..L4 K=256, L5 K=320, L6,L7 K=256, OUT K=256 (NF=1, n padded to 16)
#define OFF_L0   0
#define OFF_L1   16384
#define OFF_L2   81920
#define OFF_L3   147456
#define OFF_L4   212992
#define OFF_L5   278528
#define OFF_L6   360448
#define OFF_L7   425984
#define OFF_OUT  491520
#define TOT_HALVES 495616
#define TOT_GROUPS (TOT_HALVES / 8)   // 61952

__global__ void nerf_prep(const float* __restrict__ W0, const float* __restrict__ W1,
                          const float* __restrict__ W2, const float* __restrict__ W3,
                          const float* __restrict__ W4, const float* __restrict__ W5,
                          const float* __restrict__ W6, const float* __restrict__ W7,
                          const float* __restrict__ Wout, _Float16* __restrict__ wf)
{
    int g = blockIdx.x * 256 + threadIdx.x;     // one 8-half fragment group
    if (g >= TOT_GROUPS) return;

    const int bounds[10] = {0, 2048, 10240, 18432, 26624, 34816, 45056, 53248, 61440, 61952};
    const float* Ws[9] = {W0, W1, W2, W3, W4, W5, W6, W7, Wout};

    int L = 0;
    while (L < 8 && g >= bounds[L + 1]) ++L;

    int t    = g - bounds[L];
    int lane = t & 63;
    int q    = t >> 6;
    int NF   = (L == 8) ? 1 : 16;
    int nf   = q % NF;
    int ks   = q / NF;
    int n    = nf * 16 + (lane & 15);
    int k0   = ks * 32 + (lane >> 4) * 8;

    const float* W = Ws[L];
    h8 v;
#pragma unroll
    for (int i = 0; i < 8; ++i) {
        int k = k0 + i;
        float val = 0.f;
        if (L == 0) {
            if (k < 63) val = W[k * 256 + n];                 // 63x256, pad k=63
        } else if (L == 5) {
            // k' < 256 -> h part (orig row 63+k'); k' >= 256 -> x part (orig row k'-256)
            if (k < 256)            val = W[(63 + k) * 256 + n];
            else if ((k - 256) < 63) val = W[(k - 256) * 256 + n];
        } else if (L == 8) {
            if (n < 4) val = W[k * 4 + n];                    // 256x4, pad n to 16
        } else {
            val = W[k * 256 + n];                             // 256x256
        }
        v[i] = (_Float16)val;
    }
    *(h8*)(wf + (size_t)g * 8) = v;
}

__device__ __forceinline__ const h8* bfrag_ptr(const _Float16* __restrict__ w,
                                               int ks, int wid, int nf, int lane)
{
    return (const h8*)(w + (size_t)((ks * 16 + (wid * 4 + nf)) * 64 + lane) * 8);
}

// MODE: 0 = A from hbuf, 1 = A from xbuf (layer 0), 2 = hbuf then xbuf (layer 5)
// pf: depth-2 prefetch buffers; on entry pf[0]/pf[1] hold this layer's ks=0/1
// B-frags; on exit (!LAST) they hold the NEXT layer's ks=0/1 frags.
template <int KSTEPS, int MODE, bool LAST>
__device__ __forceinline__ void mlp_layer(_Float16 (&hbuf)[64][264], _Float16 (&xbuf)[64][72],
                                          const _Float16* __restrict__ wfrag,
                                          const _Float16* __restrict__ wnext,
                                          const float* __restrict__ bias,
                                          int wid, int lane, h8 (&pf)[2][4])
{
    const int lg = lane >> 4, ln = lane & 15;

    // bias early (no fresh global load in the epilogue)
    float bv[4];
#pragma unroll
    for (int nf = 0; nf < 4; ++nf) bv[nf] = bias[wid * 64 + nf * 16 + ln];

    f4 acc[4][4];
#pragma unroll
    for (int mf = 0; mf < 4; ++mf)
#pragma unroll
        for (int nf = 0; nf < 4; ++nf)
#pragma unroll
            for (int i = 0; i < 4; ++i) acc[mf][nf][i] = 0.f;

#pragma unroll
    for (int ks = 0; ks < KSTEPS; ++ks) {
#pragma unroll
        for (int mf = 0; mf < 4; ++mf) {
            const _Float16* ap;
            if constexpr (MODE == 1) {
                ap = &xbuf[mf * 16 + ln][ks * 32 + lg * 8];
            } else if constexpr (MODE == 2) {
                ap = (ks < 8) ? &hbuf[mf * 16 + ln][ks * 32 + lg * 8]
                              : &xbuf[mf * 16 + ln][(ks - 8) * 32 + lg * 8];
            } else {
                ap = &hbuf[mf * 16 + ln][ks * 32 + lg * 8];
            }
            h8 afr = *(const h8*)ap;
#pragma unroll
            for (int nf = 0; nf < 4; ++nf)
                acc[mf][nf] = __builtin_amdgcn_mfma_f32_16x16x32_f16(afr, pf[ks & 1][nf], acc[mf][nf], 0, 0, 0);
        }
        // refill the buffer just consumed: ks+2 of this layer, or ks=0/1 of next
        if (ks + 2 < KSTEPS) {
#pragma unroll
            for (int nf = 0; nf < 4; ++nf)
                pf[ks & 1][nf] = *bfrag_ptr(wfrag, ks + 2, wid, nf, lane);
        } else if constexpr (!LAST) {
#pragma unroll
            for (int nf = 0; nf < 4; ++nf)
                pf[ks & 1][nf] = *bfrag_ptr(wnext, ks + 2 - KSTEPS, wid, nf, lane);
        }
    }

    __syncthreads();   // everyone done reading hbuf -> safe to overwrite in place

#pragma unroll
    for (int nf = 0; nf < 4; ++nf) {
#pragma unroll
        for (int mf = 0; mf < 4; ++mf) {
#pragma unroll
            for (int i = 0; i < 4; ++i) {
                float v = acc[mf][nf][i] + bv[nf];  // bias in fp32
                v = fmaxf(v, 0.f);                  // relu in fp32
                // C layout (m89-verified): row = (lane>>4)*4 + reg, col = lane&15
                hbuf[mf * 16 + lg * 4 + i][wid * 64 + nf * 16 + ln] = (_Float16)v;
            }
        }
    }
    __syncthreads();
}

__global__ __launch_bounds__(256, 3) void nerf_fused(
    const float* __restrict__ x,
    const float* __restrict__ b0, const float* __restrict__ b1, const float* __restrict__ b2,
    const float* __restrict__ b3, const float* __restrict__ b4, const float* __restrict__ b5,
    const float* __restrict__ b6, const float* __restrict__ b7, const float* __restrict__ bout,
    const _Float16* __restrict__ wf,
    float* __restrict__ out)
{
    __shared__ _Float16 hbuf[64][264];   // 256 + 8 pad halves per row
    __shared__ _Float16 xbuf[64][72];    // 64 (63 real + 1 zero) + pad

    const int tid  = threadIdx.x;
    const int wid  = tid >> 6;
    const int lane = tid & 63;
    const int lg   = lane >> 4, ln = lane & 15;
    const int row0 = blockIdx.x * 64;

    // prologue: issue L0's ks=0,1 B-frag loads first (in flight during x-staging)
    h8 pf[2][4];
#pragma unroll
    for (int s = 0; s < 2; ++s)
#pragma unroll
        for (int nf = 0; nf < 4; ++nf)
            pf[s][nf] = *bfrag_ptr(wf + OFF_L0, s, wid, nf, lane);

    // stage x[:, 0:63] -> fp16, zero-pad col 63
    for (int idx = tid; idx < 64 * 64; idx += 256) {
        int r = idx >> 6, c = idx & 63;
        float v = (c < 63) ? x[(size_t)(row0 + r) * 90 + c] : 0.f;
        xbuf[r][c] = (_Float16)v;
    }
    __syncthreads();

    mlp_layer<2, 1, false>(hbuf, xbuf, wf + OFF_L0, wf + OFF_L1, b0, wid, lane, pf);
    mlp_layer<8, 0, false>(hbuf, xbuf, wf + OFF_L1, wf + OFF_L2, b1, wid, lane, pf);
    mlp_layer<8, 0, false>(hbuf, xbuf, wf + OFF_L2, wf + OFF_L3, b2, wid, lane, pf);
    mlp_layer<8, 0, false>(hbuf, xbuf, wf + OFF_L3, wf + OFF_L4, b3, wid, lane, pf);
    mlp_layer<8, 0, false>(hbuf, xbuf, wf + OFF_L4, wf + OFF_L5, b4, wid, lane, pf);
    mlp_layer<10, 2, false>(hbuf, xbuf, wf + OFF_L5, wf + OFF_L6, b5, wid, lane, pf);
    mlp_layer<8, 0, false>(hbuf, xbuf, wf + OFF_L6, wf + OFF_L7, b6, wid, lane, pf);
    mlp_layer<8, 0, true>(hbuf, xbuf, wf + OFF_L7, wf + OFF_L7, b7, wid, lane, pf);

    // output layer 256 -> 4 (padded to 16 cols), row-split: wave wid owns rows [16*wid, 16*wid+16)
    f4 oacc;
#pragma unroll
    for (int i = 0; i < 4; ++i) oacc[i] = 0.f;
#pragma unroll
    for (int ks = 0; ks < 8; ++ks) {
        h8 bfr = *(const h8*)(wf + OFF_OUT + (size_t)(ks * 64 + lane) * 8);
        h8 afr = *(const h8*)&hbuf[wid * 16 + ln][ks * 32 + lg * 8];
        oacc = __builtin_amdgcn_mfma_f32_16x16x32_f16(afr, bfr, oacc, 0, 0, 0);
    }
    if (ln < 4) {
        float bo = bout[ln];
#pragma unroll
        for (int i = 0; i < 4; ++i) {
            int r = row0 + wid * 16 + lg * 4 + i;
            out[(size_t)r * 4 + ln] = oacc[i] + bo;
        }
    }
}

extern "C" void kernel_launch(void* const* d_in, const int* in_sizes, int n_in,
                              void* d_out, int out_size, void* d_ws, size_t ws_size,
                              hipStream_t stream)
{
    const float* x = (const float*)d_in[0];
    const float* W[9];
    const float* b[9];
    for (int i = 0; i < 8; ++i) {
        W[i] = (const float*)d_in[1 + 2 * i];
        b[i] = (const float*)d_in[2 + 2 * i];
    }
    W[8] = (const float*)d_in[17];   // Wout
    b[8] = (const float*)d_in[18];   // bout

    _Float16* wf = (_Float16*)d_ws;

    nerf_prep<<<(TOT_GROUPS + 255) / 256, 256, 0, stream>>>(
        W[0], W[1], W[2], W[3], W[4], W[5], W[6], W[7], W[8], wf);

    nerf_fused<<<262144 / 64, 256, 0, stream>>>(
        x, b[0], b[1], b[2], b[3], b[4], b[5], b[6], b[7], b[8], wf,
        (float*)d_out);
}